// Round 3
// baseline (337.176 us; speedup 1.0000x reference)
//
#include <hip/hip_runtime.h>
#include <stdint.h>

// ---------------------------------------------------------------------------
// HaloAttn: BLOCK=8, HALO=3, WIN=14, NH=8, DH=32, DIM=256, DV=256
// ALL inputs and the output are float32 (per reference); internal compute is
// bf16 MFMA (threshold is 2% of max|ref|).
// x:(4,256,128,128) w_q:(256,256) w_kv:(512,256) h_rel/w_rel:(27,32)
// out:(4,256,128,128) fp32
// ---------------------------------------------------------------------------

typedef short bf16s;                                      // raw bf16 storage
typedef bf16s bf16x8 __attribute__((ext_vector_type(8))); // MFMA A/B frag
typedef float f32x4  __attribute__((ext_vector_type(4))); // MFMA C/D frag
typedef unsigned int u32x4 __attribute__((ext_vector_type(4)));

#define MFMA16(a, b, c) __builtin_amdgcn_mfma_f32_16x16x32_bf16(a, b, c, 0, 0, 0)
#define SCALE_QK 0.17677669529663687f
#define LOG2E 1.4426950408889634f
#define NEG_BIG (-1e30f)

__device__ __forceinline__ void async16(void* lds, const void* g) {
  __builtin_amdgcn_global_load_lds(
      (const __attribute__((address_space(1))) unsigned int*)g,
      (__attribute__((address_space(3))) unsigned int*)lds, 16, 0, 0);
}

__device__ __forceinline__ bf16s f2b(float f) {
  unsigned int u = __builtin_bit_cast(unsigned int, f);
  u = (u + 0x7fffu + ((u >> 16) & 1u)) >> 16;
  return (bf16s)u;
}

// ---------------------------------------------------------------------------
// K_convert: fp32 -> bf16 for w_q (65536), w_kv (131072), rel tables (2048,
// layout [relid][32 r][32 d], rows 27..31 zeroed;  relid 0=width, 1=height)
// ---------------------------------------------------------------------------
__global__ __launch_bounds__(256) void k_convert(const float* __restrict__ wq,
                                                 const float* __restrict__ wkv,
                                                 const float* __restrict__ hrel,
                                                 const float* __restrict__ wrel,
                                                 bf16s* __restrict__ wq_b,
                                                 bf16s* __restrict__ wkv_b,
                                                 bf16s* __restrict__ rel_b) {
  int i = blockIdx.x * 256 + threadIdx.x;   // grid 776 * 256 = 198656 exact
  if (i < 65536) {
    wq_b[i] = f2b(wq[i]);
  } else if (i < 196608) {
    int j = i - 65536;
    wkv_b[j] = f2b(wkv[j]);
  } else {
    int r2 = i - 196608;                    // [0,2048)
    int relid = r2 >> 10, r = (r2 >> 5) & 31, d = r2 & 31;
    const float* src = relid ? hrel : wrel;
    rel_b[r2] = (r < 27) ? f2b(src[r * 32 + d]) : (bf16s)0;
  }
}

// ---------------------------------------------------------------------------
// K0: x fp32 (b,c,p) -> xT bf16 (b,p,c)
// ---------------------------------------------------------------------------
__global__ __launch_bounds__(256) void k_transpose(const float* __restrict__ x,
                                                   bf16s* __restrict__ xT) {
  __shared__ bf16s tile[64][72];
  const int ct = blockIdx.x, pt = blockIdx.y, b = blockIdx.z;
  const int t = threadIdx.x;
  const int r0 = t >> 3, c8 = (t & 7) * 8;
  const float* src = x + ((size_t)b * 256 + ct * 64) * 16384 + (size_t)pt * 64;
#pragma unroll
  for (int pass = 0; pass < 2; ++pass) {
    int r = pass * 32 + r0;                 // channel-local
    const float4* sp = (const float4*)(src + (size_t)r * 16384 + c8);
    float4 f0 = sp[0], f1 = sp[1];
    bf16x8 v;
    v[0] = f2b(f0.x); v[1] = f2b(f0.y); v[2] = f2b(f0.z); v[3] = f2b(f0.w);
    v[4] = f2b(f1.x); v[5] = f2b(f1.y); v[6] = f2b(f1.z); v[7] = f2b(f1.w);
    *(bf16x8*)&tile[r][c8] = v;             // tile[ch][px]
  }
  __syncthreads();
  bf16s* dst = xT + ((size_t)b * 16384 + pt * 64) * 256 + ct * 64;
#pragma unroll
  for (int pass = 0; pass < 2; ++pass) {
    int p = pass * 32 + r0;                 // pixel-local
    bf16x8 v;
#pragma unroll
    for (int u = 0; u < 8; ++u) v[u] = tile[c8 + u][p];
    *(bf16x8*)(dst + (size_t)p * 256 + c8) = v;
  }
}

// ---------------------------------------------------------------------------
// K0b: zero the 3-pixel halo border of kv_ws [b][134][134][512]
// ---------------------------------------------------------------------------
__global__ __launch_bounds__(256) void k_zero_border(bf16s* __restrict__ kv) {
  const int gid = blockIdx.x * 256 + threadIdx.x;  // 4*1572*64 total
  const int chunk = gid & 63;
  const int rest = gid >> 6;
  const int b = rest / 1572, pxi = rest % 1572;
  int y, x;
  if (pxi < 804) {                // top/bottom 3 rows, full width
    int r = pxi / 134;
    x = pxi % 134;
    y = (r < 3) ? r : 128 + r;    // 0,1,2,131,132,133
  } else {                        // middle rows, left/right 3 cols
    int p2 = pxi - 804;
    y = 3 + p2 / 6;
    int xi = p2 % 6;
    x = (xi < 3) ? xi : 128 + xi;
  }
  u32x4 z = {0, 0, 0, 0};
  *(u32x4*)(kv + (((size_t)b * 134 + y) * 134 + x) * 512 + chunk * 8) = z;
}

// ---------------------------------------------------------------------------
// K1: qkv projection GEMM (all-bf16).  C[o][p] = sum_c W[o][c] * xT[b][p][c]
// ---------------------------------------------------------------------------
__global__ __launch_bounds__(256) void k_qkv(const bf16s* __restrict__ wq,
                                             const bf16s* __restrict__ wkv,
                                             const bf16s* __restrict__ xT,
                                             bf16s* __restrict__ q_ws,
                                             bf16s* __restrict__ kv_ws) {
  __shared__ __align__(16) bf16s smem[17408];  // A:4096 | B:4096 ; epi: 128x136
  bf16s* Al = smem;
  bf16s* Bl = smem + 4096;
  const int mt = blockIdx.x, y = blockIdx.y, b = blockIdx.z;
  const int t = threadIdx.x;
  const int wv = t >> 6, lane = t & 63, g = lane >> 4, l15 = lane & 15;
  const int wm = wv & 1, wn = wv >> 1;
  const bf16s* Ag = (mt < 2) ? (wq + mt * 128 * 256) : (wkv + (mt - 2) * 128 * 256);
  const bf16s* Bg = xT + ((size_t)b * 16384 + y * 128) * 256;

  f32x4 acc[4][4];
#pragma unroll
  for (int i = 0; i < 4; ++i)
#pragma unroll
    for (int j = 0; j < 4; ++j) acc[i][j] = (f32x4){0.f, 0.f, 0.f, 0.f};

  for (int kc = 0; kc < 8; ++kc) {
    __syncthreads();
#pragma unroll
    for (int hh = 0; hh < 2; ++hh) {
      int tt = hh * 256 + t;
      int row = tt >> 2, k8 = (tt & 3) * 8;
      async16((char*)Al + hh * 4096 + wv * 1024, Ag + row * 256 + kc * 32 + k8);
      async16((char*)Bl + hh * 4096 + wv * 1024, Bg + row * 256 + kc * 32 + k8);
    }
    __syncthreads();  // drains vmcnt(0)
    bf16x8 af[4], bfr[4];
#pragma unroll
    for (int mi = 0; mi < 4; ++mi)
      af[mi] = *(const bf16x8*)&Al[(wm * 64 + mi * 16 + l15) * 32 + g * 8];
#pragma unroll
    for (int ni = 0; ni < 4; ++ni)
      bfr[ni] = *(const bf16x8*)&Bl[(wn * 64 + ni * 16 + l15) * 32 + g * 8];
#pragma unroll
    for (int mi = 0; mi < 4; ++mi)
#pragma unroll
      for (int ni = 0; ni < 4; ++ni)
        acc[mi][ni] = MFMA16(af[mi], bfr[ni], acc[mi][ni]);
  }

  __syncthreads();
  bf16s* Cl = smem;  // [px 128][o 128], stride 136
#pragma unroll
  for (int mi = 0; mi < 4; ++mi)
#pragma unroll
    for (int ni = 0; ni < 4; ++ni)
#pragma unroll
      for (int rg = 0; rg < 4; ++rg) {
        int m = wm * 64 + mi * 16 + g * 4 + rg;   // o-local
        int n = wn * 64 + ni * 16 + l15;          // px
        Cl[n * 136 + m] = f2b(acc[mi][ni][rg]);
      }
  __syncthreads();

  if (mt < 2) {  // q channels: o = head*32 + d
#pragma unroll
    for (int hh = 0; hh < 2; ++hh) {
      int rid = hh * 256 + t;                     // 512 items: 128px x 4 heads
      int head = rid >> 7, bx = (rid >> 3) & 15, wc = rid & 7;
      int px = bx * 8 + wc;
      bf16s* dst = q_ws +
          ((((size_t)(b * 8 + mt * 4 + head) * 256 + (y >> 3) * 16 + bx) * 64 +
            (y & 7) * 8 + wc)) * 32;
#pragma unroll
      for (int c4 = 0; c4 < 4; ++c4)
        *(bf16x8*)(dst + c4 * 8) = *(const bf16x8*)&Cl[px * 136 + head * 32 + c4 * 8];
    }
  } else {       // kv channels: 256 items = 128px x 2 halves (64ch each)
    int px = t >> 1, half = t & 1;
    bf16s* dst = kv_ws + (((size_t)b * 134 + y + 3) * 134 + px + 3) * 512 +
                 (mt - 2) * 128 + half * 64;
#pragma unroll
    for (int c8 = 0; c8 < 8; ++c8)
      *(bf16x8*)(dst + c8 * 8) = *(const bf16x8*)&Cl[px * 136 + half * 64 + c8 * 8];
  }
}

// ---------------------------------------------------------------------------
// K2: attention. One wg (4 waves) per (bh, block). 196 keys padded to 208/224.
// ---------------------------------------------------------------------------
__global__ __launch_bounds__(256) void k_attn(const bf16s* __restrict__ q_ws,
                                              const bf16s* __restrict__ kv_ws,
                                              const bf16s* __restrict__ rel_b,
                                              float* __restrict__ outp) {
  __shared__ __align__(16) bf16s q_lds[2048];      // [qpos 64][d 32]
  __shared__ __align__(16) bf16s rel_lds[2048];    // [2][32 r][32 d]
  __shared__ __align__(16) bf16s kvu[7168];        // k:[208][32] then vT:[32][224]
  __shared__ __align__(16) bf16s p_lds[64 * 232];  // P in A-layout, stride 232
  __shared__ float RWl[64 * 33];                   // q . width_rel[r]
  __shared__ float RHl[64 * 33];                   // q . height_rel[r]
  __shared__ __align__(16) float o_ldsf[32 * 72];  // [d 32][qpos 64] pad 72

  const int t = threadIdx.x;
  const int wv = t >> 6, lane = t & 63, g = lane >> 4, l15 = lane & 15;

  // XCD-aware swizzle: 4 adjacent bx per XCD slot for KV L2 reuse
  int wgid = blockIdx.x;
  int xcd = wgid & 7, chnk = wgid >> 3;
  int bxlo = chnk & 3, rest = chnk >> 2;
  int c = xcd * 256 + rest;               // 0..2047
  int bx = (c & 3) * 4 + bxlo;
  int byy = (c >> 2) & 15;
  int bh = c >> 6;                        // 0..31
  int b = bh >> 3, hd = bh & 7;
  int blk = byy * 16 + bx;

  // --- stage q (async, 4KB linear) ---
  const bf16s* qg = q_ws + ((size_t)bh * 256 + blk) * 2048;
  async16((char*)q_lds + wv * 1024, qg + t * 8);

  // --- stage rel embeddings (pre-padded bf16 buffer, 2048 elems) ---
  *(bf16x8*)&rel_lds[t * 8] = *(const bf16x8*)(rel_b + t * 8);

  // --- stage k (196 pos x 32 d), zero pad rows, zero P pad cols ---
  const bf16s* kvb = kv_ws + (((size_t)b * 134 + byy * 8) * 134 + bx * 8) * 512 + hd * 64;
  for (int idx = t; idx < 784; idx += 256) {
    int pos = idx >> 2, ch = idx & 3;
    int i = pos / 14, j = pos - i * 14;
    bf16x8 v = *(const bf16x8*)(kvb + (size_t)(i * 134 + j) * 512 + ch * 8);
    *(bf16x8*)&kvu[pos * 32 + ch * 8] = v;
  }
  {
    u32x4 z = {0, 0, 0, 0};
    if (t < 48) { int pos = 196 + (t >> 2), ch = t & 3; *(u32x4*)&kvu[pos * 32 + ch * 8] = z; }
    if (t < 128) { int row = t >> 1, c8 = (t & 1) * 8; *(u32x4*)&p_lds[row * 232 + 208 + c8] = z; }
  }
  __syncthreads();

  // --- QK^T (13 MFMA) + rel logits (4 MFMA) ---
  bf16x8 aq = *(const bf16x8*)&q_lds[(wv * 16 + l15) * 32 + g * 8];
  f32x4 acc[13];
#pragma unroll
  for (int nt = 0; nt < 13; ++nt) acc[nt] = (f32x4){0.f, 0.f, 0.f, 0.f};
#pragma unroll
  for (int nt = 0; nt < 13; ++nt) {
    bf16x8 bk = *(const bf16x8*)&kvu[(nt * 16 + l15) * 32 + g * 8];
    acc[nt] = MFMA16(aq, bk, acc[nt]);
  }
  f32x4 aw[2], ah[2];
#pragma unroll
  for (int ti = 0; ti < 2; ++ti) {
    bf16x8 bw = *(const bf16x8*)&rel_lds[(ti * 16 + l15) * 32 + g * 8];
    bf16x8 bh2 = *(const bf16x8*)&rel_lds[1024 + (ti * 16 + l15) * 32 + g * 8];
    f32x4 zz = (f32x4){0.f, 0.f, 0.f, 0.f};
    aw[ti] = MFMA16(aq, bw, zz);
    ah[ti] = MFMA16(aq, bh2, zz);
  }
  const int qbase = wv * 16 + g * 4;   // this lane's 4 q-rows
#pragma unroll
  for (int rg = 0; rg < 4; ++rg) {
    RWl[(qbase + rg) * 33 + l15]      = aw[0][rg];
    RWl[(qbase + rg) * 33 + 16 + l15] = aw[1][rg];
    RHl[(qbase + rg) * 33 + l15]      = ah[0][rg];
    RHl[(qbase + rg) * 33 + 16 + l15] = ah[1][rg];
  }
  __syncthreads();  // all k reads done -> kvu reusable as vT; RW/RH visible

  // --- stage v transposed: vT[d][pos] ---
  bf16s* vT = kvu;
  for (int idx = t; idx < 784; idx += 256) {
    int pos = idx >> 2, ch = idx & 3;
    int i = pos / 14, j = pos - i * 14;
    bf16x8 v = *(const bf16x8*)(kvb + (size_t)(i * 134 + j) * 512 + 32 + ch * 8);
#pragma unroll
    for (int u = 0; u < 8; ++u) vT[(ch * 8 + u) * 224 + pos] = v[u];
  }
  for (int idx = t; idx < 896; idx += 256) {  // zero pad cols 196..223
    int d = idx / 28, cc = 196 + idx - d * 28;
    vT[d * 224 + cc] = 0;
  }

  // --- softmax with rel gather (skew index 13+j-w / 13+i-h) ---
  const int hq = qbase >> 3;     // constant across rg (qbase%8 in {0,4})
  const int wq0 = qbase & 7;
  float mx[4], sm[4];
#pragma unroll
  for (int rg = 0; rg < 4; ++rg) mx[rg] = NEG_BIG;
#pragma unroll
  for (int nt = 0; nt < 13; ++nt) {
    int col = nt * 16 + l15;
    int i = col / 14, j = col - i * 14;
    bool valid = col < 196;
    int iw0 = 13 + j - wq0;
    int ih0 = 13 + i - hq;
#pragma unroll
    for (int rg = 0; rg < 4; ++rg) {
      float v;
      if (valid)
        v = acc[nt][rg] * SCALE_QK + RWl[(qbase + rg) * 33 + iw0 - rg] +
            RHl[(qbase + rg) * 33 + ih0];
      else
        v = NEG_BIG;
      acc[nt][rg] = v;
      mx[rg] = fmaxf(mx[rg], v);
    }
  }
#pragma unroll
  for (int rg = 0; rg < 4; ++rg) {
    float m2 = mx[rg];
    m2 = fmaxf(m2, __shfl_xor(m2, 1, 16));
    m2 = fmaxf(m2, __shfl_xor(m2, 2, 16));
    m2 = fmaxf(m2, __shfl_xor(m2, 4, 16));
    m2 = fmaxf(m2, __shfl_xor(m2, 8, 16));
    mx[rg] = m2;
    sm[rg] = 0.f;
  }
#pragma unroll
  for (int nt = 0; nt < 13; ++nt)
#pragma unroll
    for (int rg = 0; rg < 4; ++rg) {
      float e = exp2f((acc[nt][rg] - mx[rg]) * LOG2E);
      acc[nt][rg] = e;
      sm[rg] += e;
    }
#pragma unroll
  for (int rg = 0; rg < 4; ++rg) {
    float s = sm[rg];
    s += __shfl_xor(s, 1, 16);
    s += __shfl_xor(s, 2, 16);
    s += __shfl_xor(s, 4, 16);
    s += __shfl_xor(s, 8, 16);
    sm[rg] = __builtin_amdgcn_rcpf(s);
  }
#pragma unroll
  for (int nt = 0; nt < 13; ++nt) {
    int col = nt * 16 + l15;
#pragma unroll
    for (int rg = 0; rg < 4; ++rg)
      p_lds[(qbase + rg) * 232 + col] = f2b(acc[nt][rg] * sm[rg]);
  }
  __syncthreads();  // P + vT ready

  // --- PV: O(64x32) = P(64x224) * V(224x32) ---
  f32x4 oa[2];
  oa[0] = (f32x4){0.f, 0.f, 0.f, 0.f};
  oa[1] = (f32x4){0.f, 0.f, 0.f, 0.f};
#pragma unroll
  for (int ks = 0; ks < 7; ++ks) {
    bf16x8 ap = *(const bf16x8*)&p_lds[(wv * 16 + l15) * 232 + ks * 32 + g * 8];
#pragma unroll
    for (int n2 = 0; n2 < 2; ++n2) {
      bf16x8 bv = *(const bf16x8*)&vT[(n2 * 16 + l15) * 224 + ks * 32 + g * 8];
      oa[n2] = MFMA16(ap, bv, oa[n2]);
    }
  }
#pragma unroll
  for (int n2 = 0; n2 < 2; ++n2)
#pragma unroll
    for (int rg = 0; rg < 4; ++rg)
      o_ldsf[(n2 * 16 + l15) * 72 + qbase + rg] = oa[n2][rg];
  __syncthreads();

  // --- store fp32: out[b][hd*32+d][byy*8+hh][bx*8 .. +8] ---
  {
    int d = t >> 3, hh = t & 7;
    const float4* s4 = (const float4*)&o_ldsf[d * 72 + hh * 8];
    float4* o4 = (float4*)(outp +
        ((((size_t)b * 256 + hd * 32 + d) * 128 + byy * 8 + hh) * 128 + bx * 8));
    o4[0] = s4[0];
    o4[1] = s4[1];
  }
}

// ---------------------------------------------------------------------------
extern "C" void kernel_launch(void* const* d_in, const int* in_sizes, int n_in,
                              void* d_out, int out_size, void* d_ws, size_t ws_size,
                              hipStream_t stream) {
  (void)in_sizes; (void)n_in; (void)out_size; (void)ws_size;
  const float* x    = (const float*)d_in[0];
  const float* wq   = (const float*)d_in[1];
  const float* wkv  = (const float*)d_in[2];
  const float* hrel = (const float*)d_in[3];
  const float* wrel = (const float*)d_in[4];
  float* outp = (float*)d_out;

  bf16s* xT    = (bf16s*)d_ws;        // 16,777,216 elems (33.5 MB)
  bf16s* q_ws  = xT + 16777216;       // 16,777,216 elems (33.5 MB)
  bf16s* kv_ws = q_ws + 16777216;     // 36,773,888 elems (73.5 MB)
  bf16s* wq_b  = kv_ws + 36773888;    //     65,536
  bf16s* wkv_b = wq_b + 65536;        //    131,072
  bf16s* rel_b = wkv_b + 131072;      //      2,048

  hipLaunchKernelGGL(k_convert,    dim3(776),      dim3(256), 0, stream,
                     wq, wkv, hrel, wrel, wq_b, wkv_b, rel_b);
  hipLaunchKernelGGL(k_transpose,  dim3(4, 256, 4), dim3(256), 0, stream, x, xT);
  hipLaunchKernelGGL(k_zero_border, dim3(1572),     dim3(256), 0, stream, kv_ws);
  hipLaunchKernelGGL(k_qkv,        dim3(6, 128, 4), dim3(256), 0, stream,
                     wq_b, wkv_b, xT, q_ws, kv_ws);
  hipLaunchKernelGGL(k_attn,       dim3(8192),      dim3(256), 0, stream,
                     q_ws, kv_ws, rel_b, outp);
}

// Round 4
// 300.652 us; speedup vs baseline: 1.1215x; 1.1215x over previous
//
#include <hip/hip_runtime.h>
#include <stdint.h>

// ---------------------------------------------------------------------------
// HaloAttn: BLOCK=8, HALO=3, WIN=14, NH=8, DH=32, DIM=256, DV=256
// fp32 in/out; internal bf16 MFMA.
// ---------------------------------------------------------------------------

typedef short bf16s;                                      // raw bf16 storage
typedef bf16s bf16x8 __attribute__((ext_vector_type(8))); // MFMA A/B frag
typedef float f32x4  __attribute__((ext_vector_type(4))); // MFMA C/D frag
typedef unsigned int u32x4 __attribute__((ext_vector_type(4)));

#define MFMA16(a, b, c) __builtin_amdgcn_mfma_f32_16x16x32_bf16(a, b, c, 0, 0, 0)
#define SCALE_QK 0.17677669529663687f
#define LOG2E 1.4426950408889634f
#define EXP_SHIFT 11.541560327111707f   // 8 * log2(e)

__device__ __forceinline__ void async16(void* lds, const void* g) {
  __builtin_amdgcn_global_load_lds(
      (const __attribute__((address_space(1))) unsigned int*)g,
      (__attribute__((address_space(3))) unsigned int*)lds, 16, 0, 0);
}

__device__ __forceinline__ bf16s f2b(float f) {
  unsigned int u = __builtin_bit_cast(unsigned int, f);
  u = (u + 0x7fffu + ((u >> 16) & 1u)) >> 16;
  return (bf16s)u;
}

// ---------------------------------------------------------------------------
// K_convert: fp32 -> bf16 weights + rel tables ([relid][32r][32d], rows>=27=0)
// ---------------------------------------------------------------------------
__global__ __launch_bounds__(256) void k_convert(const float* __restrict__ wq,
                                                 const float* __restrict__ wkv,
                                                 const float* __restrict__ hrel,
                                                 const float* __restrict__ wrel,
                                                 bf16s* __restrict__ wq_b,
                                                 bf16s* __restrict__ wkv_b,
                                                 bf16s* __restrict__ rel_b) {
  int i = blockIdx.x * 256 + threadIdx.x;   // grid 776 * 256 = 198656 exact
  if (i < 65536) {
    wq_b[i] = f2b(wq[i]);
  } else if (i < 196608) {
    int j = i - 65536;
    wkv_b[j] = f2b(wkv[j]);
  } else {
    int r2 = i - 196608;                    // [0,2048)
    int relid = r2 >> 10, r = (r2 >> 5) & 31, d = r2 & 31;
    const float* src = relid ? hrel : wrel;
    rel_b[r2] = (r < 27) ? f2b(src[r * 32 + d]) : (bf16s)0;
  }
}

// ---------------------------------------------------------------------------
// K0: x fp32 (b,c,p) -> xT bf16 (b,p,c)
// ---------------------------------------------------------------------------
__global__ __launch_bounds__(256) void k_transpose(const float* __restrict__ x,
                                                   bf16s* __restrict__ xT) {
  __shared__ bf16s tile[64][72];
  const int ct = blockIdx.x, pt = blockIdx.y, b = blockIdx.z;
  const int t = threadIdx.x;
  const int r0 = t >> 3, c8 = (t & 7) * 8;
  const float* src = x + ((size_t)b * 256 + ct * 64) * 16384 + (size_t)pt * 64;
#pragma unroll
  for (int pass = 0; pass < 2; ++pass) {
    int r = pass * 32 + r0;
    const float4* sp = (const float4*)(src + (size_t)r * 16384 + c8);
    float4 f0 = sp[0], f1 = sp[1];
    bf16x8 v;
    v[0] = f2b(f0.x); v[1] = f2b(f0.y); v[2] = f2b(f0.z); v[3] = f2b(f0.w);
    v[4] = f2b(f1.x); v[5] = f2b(f1.y); v[6] = f2b(f1.z); v[7] = f2b(f1.w);
    *(bf16x8*)&tile[r][c8] = v;
  }
  __syncthreads();
  bf16s* dst = xT + ((size_t)b * 16384 + pt * 64) * 256 + ct * 64;
#pragma unroll
  for (int pass = 0; pass < 2; ++pass) {
    int p = pass * 32 + r0;
    bf16x8 v;
#pragma unroll
    for (int u = 0; u < 8; ++u) v[u] = tile[c8 + u][p];
    *(bf16x8*)(dst + (size_t)p * 256 + c8) = v;
  }
}

// ---------------------------------------------------------------------------
// K0b: zero the 3-pixel halo border of kv_ws [b][134][134][512]
// ---------------------------------------------------------------------------
__global__ __launch_bounds__(256) void k_zero_border(bf16s* __restrict__ kv) {
  const int gid = blockIdx.x * 256 + threadIdx.x;  // 4*1572*64 total
  const int chunk = gid & 63;
  const int rest = gid >> 6;
  const int b = rest / 1572, pxi = rest % 1572;
  int y, x;
  if (pxi < 804) {
    int r = pxi / 134;
    x = pxi % 134;
    y = (r < 3) ? r : 128 + r;
  } else {
    int p2 = pxi - 804;
    y = 3 + p2 / 6;
    int xi = p2 % 6;
    x = (xi < 3) ? xi : 128 + xi;
  }
  u32x4 z = {0, 0, 0, 0};
  *(u32x4*)(kv + (((size_t)b * 134 + y) * 134 + x) * 512 + chunk * 8) = z;
}

// ---------------------------------------------------------------------------
// K1: qkv projection GEMM (unchanged from round 3)
// ---------------------------------------------------------------------------
__global__ __launch_bounds__(256) void k_qkv(const bf16s* __restrict__ wq,
                                             const bf16s* __restrict__ wkv,
                                             const bf16s* __restrict__ xT,
                                             bf16s* __restrict__ q_ws,
                                             bf16s* __restrict__ kv_ws) {
  __shared__ __align__(16) bf16s smem[17408];
  bf16s* Al = smem;
  bf16s* Bl = smem + 4096;
  const int mt = blockIdx.x, y = blockIdx.y, b = blockIdx.z;
  const int t = threadIdx.x;
  const int wv = t >> 6, lane = t & 63, g = lane >> 4, l15 = lane & 15;
  const int wm = wv & 1, wn = wv >> 1;
  const bf16s* Ag = (mt < 2) ? (wq + mt * 128 * 256) : (wkv + (mt - 2) * 128 * 256);
  const bf16s* Bg = xT + ((size_t)b * 16384 + y * 128) * 256;

  f32x4 acc[4][4];
#pragma unroll
  for (int i = 0; i < 4; ++i)
#pragma unroll
    for (int j = 0; j < 4; ++j) acc[i][j] = (f32x4){0.f, 0.f, 0.f, 0.f};

  for (int kc = 0; kc < 8; ++kc) {
    __syncthreads();
#pragma unroll
    for (int hh = 0; hh < 2; ++hh) {
      int tt = hh * 256 + t;
      int row = tt >> 2, k8 = (tt & 3) * 8;
      async16((char*)Al + hh * 4096 + wv * 1024, Ag + row * 256 + kc * 32 + k8);
      async16((char*)Bl + hh * 4096 + wv * 1024, Bg + row * 256 + kc * 32 + k8);
    }
    __syncthreads();
    bf16x8 af[4], bfr[4];
#pragma unroll
    for (int mi = 0; mi < 4; ++mi)
      af[mi] = *(const bf16x8*)&Al[(wm * 64 + mi * 16 + l15) * 32 + g * 8];
#pragma unroll
    for (int ni = 0; ni < 4; ++ni)
      bfr[ni] = *(const bf16x8*)&Bl[(wn * 64 + ni * 16 + l15) * 32 + g * 8];
#pragma unroll
    for (int mi = 0; mi < 4; ++mi)
#pragma unroll
      for (int ni = 0; ni < 4; ++ni)
        acc[mi][ni] = MFMA16(af[mi], bfr[ni], acc[mi][ni]);
  }

  __syncthreads();
  bf16s* Cl = smem;  // [px 128][o 128], stride 136
#pragma unroll
  for (int mi = 0; mi < 4; ++mi)
#pragma unroll
    for (int ni = 0; ni < 4; ++ni)
#pragma unroll
      for (int rg = 0; rg < 4; ++rg) {
        int m = wm * 64 + mi * 16 + g * 4 + rg;
        int n = wn * 64 + ni * 16 + l15;
        Cl[n * 136 + m] = f2b(acc[mi][ni][rg]);
      }
  __syncthreads();

  if (mt < 2) {
#pragma unroll
    for (int hh = 0; hh < 2; ++hh) {
      int rid = hh * 256 + t;
      int head = rid >> 7, bx = (rid >> 3) & 15, wc = rid & 7;
      int px = bx * 8 + wc;
      bf16s* dst = q_ws +
          ((((size_t)(b * 8 + mt * 4 + head) * 256 + (y >> 3) * 16 + bx) * 64 +
            (y & 7) * 8 + wc)) * 32;
#pragma unroll
      for (int c4 = 0; c4 < 4; ++c4)
        *(bf16x8*)(dst + c4 * 8) = *(const bf16x8*)&Cl[px * 136 + head * 32 + c4 * 8];
    }
  } else {
    int px = t >> 1, half = t & 1;
    bf16s* dst = kv_ws + (((size_t)b * 134 + y + 3) * 134 + px + 3) * 512 +
                 (mt - 2) * 128 + half * 64;
#pragma unroll
    for (int c8 = 0; c8 < 8; ++c8)
      *(bf16x8*)(dst + c8 * 8) = *(const bf16x8*)&Cl[px * 136 + half * 64 + c8 * 8];
  }
}

// ---------------------------------------------------------------------------
// K2: attention, S^T form. One wg (4 waves) per (bh, block).
// Keys tiled column-major padded: key' = j*16 + i (j=0..13 -> 14 tiles,
// i=0..13 valid, 14..15 masked).  Per lane: one q column (q = wv*16+l15),
// keys (g*4+rg) per tile.  All rel/P state wave-private in LDS.
// LDS: vT 14336 (shared) + 4 * 7168 (per-wave: RW/RH fp32 then P bf16) = 43008
// ---------------------------------------------------------------------------
__global__ __launch_bounds__(256, 3) void k_attn(const bf16s* __restrict__ q_ws,
                                                 const bf16s* __restrict__ kv_ws,
                                                 const bf16s* __restrict__ rel_b,
                                                 float* __restrict__ outp) {
  __shared__ __align__(16) char arena[43008];
  bf16s* vT = (bf16s*)arena;                         // [d 32][key' 224]
  const int t = threadIdx.x;
  const int wv = t >> 6, lane = t & 63, g = lane >> 4, l15 = lane & 15;
  char* pw = arena + 14336 + wv * 7168;              // per-wave private
  float* RWp = (float*)pw;                           // [16 q][34]
  float* RHp = RWp + 544;                            // [16 q][34]
  bf16s* pP  = (bf16s*)pw;                           // [16 q][224] (aliases RW/RH)

  // XCD-aware swizzle: 4 adjacent bx per XCD slot for KV L2 reuse
  int wgid = blockIdx.x;
  int xcd = wgid & 7, chnk = wgid >> 3;
  int bxlo = chnk & 3, rest = chnk >> 2;
  int c = xcd * 256 + rest;               // 0..2047
  int bx = (c & 3) * 4 + bxlo;
  int byy = (c >> 2) & 15;
  int bh = c >> 6;                        // 0..31
  int b = bh >> 3, hd = bh & 7;
  int blk = byy * 16 + bx;

  const bf16s* kvb = kv_ws + (((size_t)b * 134 + byy * 8) * 134 + bx * 8) * 512 + hd * 64;
  const bf16s* qg  = q_ws + ((size_t)bh * 256 + blk) * 2048;

  // --- per-lane operand fragments straight from global (L2-hot) ---
  bf16x8 aq = *(const bf16x8*)(qg + (wv * 16 + l15) * 32 + g * 8);   // B: q
  const int i_cl = (l15 < 14) ? l15 : 13;
  const bf16s* kbase = kvb + (size_t)i_cl * 68608 + g * 8;           // 134*512
  bf16x8 kf[14];
#pragma unroll
  for (int nt = 0; nt < 14; ++nt)
    kf[nt] = *(const bf16x8*)(kbase + nt * 512);                     // A: k rows
  bf16x8 wf[2], hf[2];
#pragma unroll
  for (int t16 = 0; t16 < 2; ++t16) {
    wf[t16] = *(const bf16x8*)(rel_b + (t16 * 16 + l15) * 32 + g * 8);
    hf[t16] = *(const bf16x8*)(rel_b + 1024 + (t16 * 16 + l15) * 32 + g * 8);
  }

  // --- cooperative vT staging: vT[d][j*16+i] = v[pixel(i,j)][d] ---
  for (int idx = t; idx < 784; idx += 256) {
    int pos = idx >> 2, ch = idx & 3;
    int i = pos / 14, j = pos - i * 14;
    bf16x8 v = *(const bf16x8*)(kvb + (size_t)(i * 134 + j) * 512 + 32 + ch * 8);
#pragma unroll
    for (int u = 0; u < 8; ++u) vT[(ch * 8 + u) * 224 + j * 16 + i] = v[u];
  }
  for (int idx = t; idx < 896; idx += 256) {  // zero pad cols i=14,15
    int d = idx / 28, r = idx - d * 28;
    vT[d * 224 + (r >> 1) * 16 + 14 + (r & 1)] = 0;
  }

  // --- QK^T (S^T): acc[nt] rows = keys nt*16+g*4+rg, col q ---
  f32x4 acc[14];
#pragma unroll
  for (int nt = 0; nt < 14; ++nt) acc[nt] = (f32x4){0.f, 0.f, 0.f, 0.f};
#pragma unroll
  for (int nt = 0; nt < 14; ++nt) acc[nt] = MFMA16(kf[nt], aq, acc[nt]);

  // --- rel logits: D[r][q] = q . rel[r], store to private tables ---
  {
    f32x4 zz = (f32x4){0.f, 0.f, 0.f, 0.f};
#pragma unroll
    for (int t16 = 0; t16 < 2; ++t16) {
      f32x4 rw = MFMA16(wf[t16], aq, zz);
      f32x4 rh = MFMA16(hf[t16], aq, zz);
#pragma unroll
      for (int rg = 0; rg < 4; ++rg) {
        RWp[l15 * 34 + t16 * 16 + g * 4 + rg] = rw[rg];
        RHp[l15 * 34 + t16 * 16 + g * 4 + rg] = rh[rg];
      }
    }
  }

  // --- softmax (no max-sub; fixed shift). jq=q&7, iq=q>>3 ---
  const int jq = l15 & 7;
  const int iq = wv * 2 + (l15 >> 3);
  const float* RWr = RWp + l15 * 34;
  const float* RHr = RHp + l15 * 34;
  const int ihb = 13 + g * 4 - iq;
  float h0 = RHr[ihb], h1 = RHr[ihb + 1], h2 = RHr[ihb + 2], h3 = RHr[ihb + 3];
  float sm = 0.f;
#pragma unroll
  for (int nt = 0; nt < 14; ++nt) {
    float w1 = RWr[13 + nt - jq];
    float e0 = exp2f(fmaf(fmaf(acc[nt][0], SCALE_QK, w1 + h0), LOG2E, -EXP_SHIFT));
    float e1 = exp2f(fmaf(fmaf(acc[nt][1], SCALE_QK, w1 + h1), LOG2E, -EXP_SHIFT));
    float e2 = exp2f(fmaf(fmaf(acc[nt][2], SCALE_QK, w1 + h2), LOG2E, -EXP_SHIFT));
    float e3 = exp2f(fmaf(fmaf(acc[nt][3], SCALE_QK, w1 + h3), LOG2E, -EXP_SHIFT));
    if (g == 3) { e2 = 0.f; e3 = 0.f; }   // key rows i=14,15 invalid
    sm += e0 + e1 + e2 + e3;
    acc[nt][0] = e0; acc[nt][1] = e1; acc[nt][2] = e2; acc[nt][3] = e3;
  }
  sm += __shfl_xor(sm, 16);
  sm += __shfl_xor(sm, 32);
  float rs = __builtin_amdgcn_rcpf(sm);

  // --- P store (wave-private rows, b64 along keys) ---
#pragma unroll
  for (int nt = 0; nt < 14; ++nt) {
    bf16s p0 = f2b(acc[nt][0] * rs), p1 = f2b(acc[nt][1] * rs);
    bf16s p2 = f2b(acc[nt][2] * rs), p3 = f2b(acc[nt][3] * rs);
    unsigned int lo = (unsigned short)p0 | ((unsigned int)(unsigned short)p1 << 16);
    unsigned int hi = (unsigned short)p2 | ((unsigned int)(unsigned short)p3 << 16);
    *(uint2*)(pP + l15 * 224 + nt * 16 + g * 4) = make_uint2(lo, hi);
  }

  __syncthreads();  // vT staged by all threads; P/RW wave-local

  // --- PV: O^T[d][q] = sum_key V^T[d][key] P[q][key] ---
  f32x4 oa0 = (f32x4){0.f, 0.f, 0.f, 0.f};
  f32x4 oa1 = (f32x4){0.f, 0.f, 0.f, 0.f};
#pragma unroll
  for (int ks = 0; ks < 7; ++ks) {
    bf16x8 bp = *(const bf16x8*)(pP + l15 * 224 + ks * 32 + g * 8);
    bf16x8 a0 = *(const bf16x8*)(vT + l15 * 224 + ks * 32 + g * 8);
    bf16x8 a1 = *(const bf16x8*)(vT + (16 + l15) * 224 + ks * 32 + g * 8);
    oa0 = MFMA16(a0, bp, oa0);
    oa1 = MFMA16(a1, bp, oa1);
  }

  // --- direct store: lane holds O[d = mt*16+g*4+rg][q = wv*16+l15] ---
  {
    int py = wv * 2 + (l15 >> 3), px = l15 & 7;
    float* ob = outp + (((size_t)(b * 256 + hd * 32) * 128 + byy * 8 + py) * 128) +
                bx * 8 + px;
#pragma unroll
    for (int rg = 0; rg < 4; ++rg) {
      ob[(size_t)(g * 4 + rg) * 16384] = oa0[rg];
      ob[(size_t)(16 + g * 4 + rg) * 16384] = oa1[rg];
    }
  }
}

// ---------------------------------------------------------------------------
extern "C" void kernel_launch(void* const* d_in, const int* in_sizes, int n_in,
                              void* d_out, int out_size, void* d_ws, size_t ws_size,
                              hipStream_t stream) {
  (void)in_sizes; (void)n_in; (void)out_size; (void)ws_size;
  const float* x    = (const float*)d_in[0];
  const float* wq   = (const float*)d_in[1];
  const float* wkv  = (const float*)d_in[2];
  const float* hrel = (const float*)d_in[3];
  const float* wrel = (const float*)d_in[4];
  float* outp = (float*)d_out;

  bf16s* xT    = (bf16s*)d_ws;        // 16,777,216 elems
  bf16s* q_ws  = xT + 16777216;       // 16,777,216 elems
  bf16s* kv_ws = q_ws + 16777216;     // 36,773,888 elems
  bf16s* wq_b  = kv_ws + 36773888;    //     65,536
  bf16s* wkv_b = wq_b + 65536;        //    131,072
  bf16s* rel_b = wkv_b + 131072;      //      2,048

  hipLaunchKernelGGL(k_convert,    dim3(776),       dim3(256), 0, stream,
                     wq, wkv, hrel, wrel, wq_b, wkv_b, rel_b);
  hipLaunchKernelGGL(k_transpose,  dim3(4, 256, 4), dim3(256), 0, stream, x, xT);
  hipLaunchKernelGGL(k_zero_border, dim3(1572),     dim3(256), 0, stream, kv_ws);
  hipLaunchKernelGGL(k_qkv,        dim3(6, 128, 4), dim3(256), 0, stream,
                     wq_b, wkv_b, xT, q_ws, kv_ws);
  hipLaunchKernelGGL(k_attn,       dim3(8192),      dim3(256), 0, stream,
                     q_ws, kv_ws, rel_b, outp);
}